// Round 7
// baseline (394.450 us; speedup 1.0000x reference)
//
#include <hip/hip_runtime.h>

// Problem constants (fixed by the reference)
#define B_   2
#define DZ   41
#define HY   400
#define WX   352
#define NVOX 40000               // = 2500 * 16 exactly
#define PD   43      // DZ+2
#define PH   402     // HY+2
#define PW   354     // WX+2
#define DO_  21
#define HO_  200
#define WO_  176
#define C1   128
#define OPP  (DO_*HO_*WO_)              // 739,200 positions per batch
#define OUT_POS (B_*OPP)                // 1,478,400
#define GRID_CELLS (B_*PD*PH*PW)        // 12,238,488 cells (uint16)
#define OUT_F4   (OUT_POS*32/4)         // 11,827,200 exact
#define GRID_F4  (GRID_CELLS*2/16)      // 1,529,811 exact
#define OMASK_F4 (OUT_POS/4)            // 369,600 exact (omask = int per pos)
#define MAXLIST  (NVOX*8)               // parity gives <= 8 positions/voxel

// Established: f32 in/out; coors int32. R6 lesson: top-5 = harness 0xAA poison
// fills (~114us, >=2/replay, time-bound). R4 best (304.5) = dumb fill + sparse
// work; R6's dense smart k_out regressed. R7: dense float4 zero + dedup
// occupied-position list + grid-stride sparse gather (no atomics on out).

// ---- valid downsample taps for one axis, from PADDED input coord ----
// o = pcoord - doff (doff 0..2) valid iff o even and 0 <= o/2 < outdim.
__device__ __forceinline__ int axis_taps(int pcoord, int outdim, int* ds, int* ps) {
    if (pcoord & 1) { ds[0] = 1; ps[0] = pcoord >> 1; return 1; }
    int h = pcoord >> 1, nu = 0;
    if (h < outdim) { ds[nu] = 0; ps[nu] = h; nu++; }
    ds[nu] = 2; ps[nu] = h - 1; nu++;
    return nu;
}

// ---- zero: out (189MB) + grid (24.5MB) + omask (5.9MB) + list counter ----
__global__ void k_zero(float4* __restrict__ o, float4* __restrict__ g,
                       float4* __restrict__ m, int* __restrict__ cntp) {
    int i = blockIdx.x * 256 + threadIdx.x;
    float4 z = make_float4(0.f, 0.f, 0.f, 0.f);
    if (i < OUT_F4)   o[i] = z;
    if (i < GRID_F4)  g[i] = z;
    if (i < OMASK_F4) m[i] = z;
    if (i == 0) *cntp = 0;
}

// ---- build: grid ids (+1, 0=empty) + dedup list of occupied out positions ----
__global__ void k_build(const int* __restrict__ coors, unsigned short* __restrict__ grid,
                        int* __restrict__ omask, int* __restrict__ list,
                        int* __restrict__ cntp) {
    int n = blockIdx.x * 256 + threadIdx.x;
    if (n >= NVOX) return;
    int b = coors[4*n+0], zp = coors[4*n+1] + 1, yp = coors[4*n+2] + 1, xp = coors[4*n+3] + 1;
    grid[((b*PD + zp)*PH + yp)*PW + xp] = (unsigned short)(n + 1);
    int dz[2], pz[2], dy[2], py[2], dx[2], px[2];
    int nz = axis_taps(zp, DO_, dz, pz);
    int ny = axis_taps(yp, HO_, dy, py);
    int nx = axis_taps(xp, WO_, dx, px);
    int bofs = b * OPP;
    for (int iz = 0; iz < nz; ++iz)
        for (int iy = 0; iy < ny; ++iy)
            for (int ix = 0; ix < nx; ++ix) {
                int p = bofs + (pz[iz]*HO_ + py[iy])*WO_ + px[ix];
                if (atomicExch(&omask[p], 1) == 0)
                    list[atomicAdd(cntp, 1)] = p;   // first toucher appends
            }
}

// ---- subm conv 1: 128 -> 16, ReLU. block = 16 voxels x 16 d; nbr in-block ----
__global__ void k_subm1(const float* __restrict__ feat, const float* __restrict__ W1,
                        const int* __restrict__ coors, const unsigned short* __restrict__ grid,
                        float* __restrict__ x1) {
    __shared__ int s_base[16];
    __shared__ int s_cnt[16];
    __shared__ int s_list[16][27];
    int base = blockIdx.x * 16;            // NVOX % 16 == 0
    int t = threadIdx.x;
    if (t < 16) {
        int n = base + t;
        int b = coors[4*n+0], z = coors[4*n+1], y = coors[4*n+2], x = coors[4*n+3];
        s_base[t] = ((b*PD + z)*PH + y)*PW + x;
        s_cnt[t] = 0;
    }
    __syncthreads();
    for (int i = t; i < 16*27; i += 256) {
        int v = i / 27, k = i % 27;
        int dz = k / 9, dy = (k / 3) % 3, dx = k % 3;
        int id = (int)grid[s_base[v] + dz*(PH*PW) + dy*PW + dx] - 1;
        if (id >= 0) {
            int pos = atomicAdd(&s_cnt[v], 1);
            s_list[v][pos] = (k << 16) | id;
        }
    }
    __syncthreads();
    int v = t >> 4, d = t & 15;
    int cnt = s_cnt[v];
    float acc = 0.f;
    for (int tap = 0; tap < cnt; ++tap) {
        int pk = s_list[v][tap];
        int k = pk >> 16, idx = pk & 0xFFFF;
        const float4* f4 = (const float4*)(feat + (size_t)idx * C1);
        const float* w = W1 + k * (C1*16) + d;
        #pragma unroll 8
        for (int c4 = 0; c4 < 32; ++c4) {
            float4 f = f4[c4];
            acc += f.x * w[(c4*4+0)*16];
            acc += f.y * w[(c4*4+1)*16];
            acc += f.z * w[(c4*4+2)*16];
            acc += f.w * w[(c4*4+3)*16];
        }
    }
    x1[(base + v)*16 + d] = fmaxf(acc, 0.f);
}

// ---- subm conv 2: 16 -> 16, ReLU. same structure ----
__global__ void k_subm2(const float* __restrict__ x1, const float* __restrict__ W2,
                        const int* __restrict__ coors, const unsigned short* __restrict__ grid,
                        float* __restrict__ x2) {
    __shared__ int s_base[16];
    __shared__ int s_cnt[16];
    __shared__ int s_list[16][27];
    int base = blockIdx.x * 16;
    int t = threadIdx.x;
    if (t < 16) {
        int n = base + t;
        int b = coors[4*n+0], z = coors[4*n+1], y = coors[4*n+2], x = coors[4*n+3];
        s_base[t] = ((b*PD + z)*PH + y)*PW + x;
        s_cnt[t] = 0;
    }
    __syncthreads();
    for (int i = t; i < 16*27; i += 256) {
        int v = i / 27, k = i % 27;
        int dz = k / 9, dy = (k / 3) % 3, dx = k % 3;
        int id = (int)grid[s_base[v] + dz*(PH*PW) + dy*PW + dx] - 1;
        if (id >= 0) {
            int pos = atomicAdd(&s_cnt[v], 1);
            s_list[v][pos] = (k << 16) | id;
        }
    }
    __syncthreads();
    int v = t >> 4, d = t & 15;
    int cnt = s_cnt[v];
    float acc = 0.f;
    for (int tap = 0; tap < cnt; ++tap) {
        int pk = s_list[v][tap];
        int k = pk >> 16, idx = pk & 0xFFFF;
        const float4* xr = (const float4*)(x1 + (size_t)idx * 16);
        float4 a0 = xr[0], a1 = xr[1], a2 = xr[2], a3 = xr[3];
        const float* w = W2 + k * 256 + d;
        acc += a0.x*w[0*16]  + a0.y*w[1*16]  + a0.z*w[2*16]  + a0.w*w[3*16]
             + a1.x*w[4*16]  + a1.y*w[5*16]  + a1.z*w[6*16]  + a1.w*w[7*16]
             + a2.x*w[8*16]  + a2.y*w[9*16]  + a2.z*w[10*16] + a2.w*w[11*16]
             + a3.x*w[12*16] + a3.y*w[13*16] + a3.z*w[14*16] + a3.w*w[15*16];
    }
    x2[(base + v)*16 + d] = fmaxf(acc, 0.f);
}

// ---- sparse gather over occupied positions: 16 -> 32, fused ReLU ----
// grid-stride; block = 8 entries x 32 channel threads
__global__ void k_gather(const float* __restrict__ x2, const float* __restrict__ W3,
                         const unsigned short* __restrict__ grid,
                         const int* __restrict__ list, const int* __restrict__ cntp,
                         float* __restrict__ out) {
    __shared__ int s_base[8];
    __shared__ int s_p[8];
    __shared__ int s_cnt[8];
    __shared__ int s_list[8][27];
    int total = *cntp;
    int t = threadIdx.x;
    for (int e0 = blockIdx.x * 8; e0 < total; e0 += gridDim.x * 8) {
        if (t < 8) {
            s_cnt[t] = 0;
            int e = e0 + t;
            int p = (e < total) ? list[e] : -1;
            s_p[t] = p;
            if (p >= 0) {
                int b  = p / OPP,        rem = p - b * OPP;
                int pz = rem / (HO_*WO_), r2 = rem - pz * (HO_*WO_);
                int py = r2 / WO_,        px = r2 - py * WO_;
                // input padded coord = 2*pout + doff <= pdim-1: always in-bounds
                s_base[t] = ((b*PD + 2*pz)*PH + 2*py)*PW + 2*px;
            }
        }
        __syncthreads();
        for (int i = t; i < 8*27; i += 256) {
            int v = i / 27;
            if (s_p[v] < 0) continue;
            int k = i % 27;
            int dz = k / 9, dy = (k / 3) % 3, dx = k % 3;
            int id = (int)grid[s_base[v] + dz*(PH*PW) + dy*PW + dx] - 1;
            if (id >= 0) {
                int pos = atomicAdd(&s_cnt[v], 1);
                s_list[v][pos] = (k << 16) | id;
            }
        }
        __syncthreads();
        int v = t >> 5, d = t & 31;
        int p = s_p[v];
        if (p >= 0) {
            float acc = 0.f;
            int cnt = s_cnt[v];
            for (int tap = 0; tap < cnt; ++tap) {
                int pk = s_list[v][tap];
                int k = pk >> 16, idx = pk & 0xFFFF;
                const float* xp = x2 + (size_t)idx * 16;
                const float* w  = W3 + k*512 + d;   // coalesced across d
                #pragma unroll
                for (int c = 0; c < 16; ++c) acc += xp[c] * w[c * 32];
            }
            out[(size_t)p * 32 + d] = fmaxf(acc, 0.f);  // 128B coalesced per entry
        }
        __syncthreads();   // protect s_* for next grid-stride iteration
    }
}

extern "C" void kernel_launch(void* const* d_in, const int* in_sizes, int n_in,
                              void* d_out, int out_size, void* d_ws, size_t ws_size,
                              hipStream_t stream) {
    const float* feat  = (const float*)d_in[0];  // f32 (N,128)
    const int*   coors = (const int*)d_in[1];    // int32 (N,4)
    const float* W1    = (const float*)d_in[2];  // f32 (27,128,16)
    const float* W2    = (const float*)d_in[3];  // f32 (27,16,16)
    const float* W3    = (const float*)d_in[4];  // f32 (27,16,32)
    float* out = (float*)d_out;                  // f32 (2,21,200,176,32)

    char* ws = (char*)d_ws;
    size_t off = 0;
    unsigned short* grid = (unsigned short*)(ws + off);
    off += (((size_t)GRID_CELLS*2) + 255) & ~(size_t)255;
    int* omask = (int*)(ws + off); off += (((size_t)OUT_POS*4) + 255) & ~(size_t)255;
    int* list  = (int*)(ws + off); off += (((size_t)MAXLIST*4) + 255) & ~(size_t)255;
    int* cntp  = (int*)(ws + off); off += 256;
    float* x1 = (float*)(ws + off); off += (((size_t)NVOX*16*4) + 255) & ~(size_t)255;
    float* x2 = (float*)(ws + off);

    k_zero <<<(OUT_F4 + 255) / 256, 256, 0, stream>>>((float4*)out, (float4*)grid,
                                                      (float4*)omask, cntp);
    k_build<<<(NVOX + 255) / 256, 256, 0, stream>>>(coors, grid, omask, list, cntp);
    k_subm1<<<NVOX / 16, 256, 0, stream>>>(feat, W1, coors, grid, x1);
    k_subm2<<<NVOX / 16, 256, 0, stream>>>(x1, W2, coors, grid, x2);
    k_gather<<<2048, 256, 0, stream>>>(x2, W3, grid, list, cntp, out);
}

// Round 8
// 331.609 us; speedup vs baseline: 1.1895x; 1.1895x over previous
//
#include <hip/hip_runtime.h>

// Problem constants (fixed by the reference)
#define B_   2
#define DZ   41
#define HY   400
#define WX   352
#define NVOX 40000               // = 2500 * 16 exactly
#define PD   43      // DZ+2
#define PH   402     // HY+2
#define PW   354     // WX+2
#define DO_  21
#define HO_  200
#define WO_  176
#define C1   128
#define OPP  (DO_*HO_*WO_)              // 739,200 positions per batch
#define GRID_CELLS (B_*PD*PH*PW)        // 12,238,488 cells (uint16)

// MODEL (fits R3-R7): dur_us includes ~230us of harness stream ops per replay
// (0xAA poison of d_ws ~757MB @114us + d_out poison + input restore). R3:
// 413.8 = 229 + k_conv 182.5 + ~2. R4 best: 304.5 = 229 + memset-out 28 +
// scatter/relu ~40 + front ~7. Own zero kernels run 2-3TB/s vs runtime fill
// 6.6TB/s -> ALWAYS use hipMemsetAsync for bulk zero. R8 = R4 structure with
// fused-nbr subm (drops k_nbrc dispatch + 8.6MB table IO).

// ---- valid downsample taps for one axis, from PADDED input coord ----
// o = pcoord - doff (doff 0..2) valid iff o even and 0 <= o/2 < outdim.
__device__ __forceinline__ int axis_taps(int pcoord, int outdim, int* ds, int* ps) {
    if (pcoord & 1) { ds[0] = 1; ps[0] = pcoord >> 1; return 1; }
    int h = pcoord >> 1, nu = 0;
    if (h < outdim) { ds[nu] = 0; ps[nu] = h; nu++; }
    ds[nu] = 2; ps[nu] = h - 1; nu++;
    return nu;
}

// ---- build padded dense grid of (voxel id + 1), 0 = empty ----
__global__ void k_build(const int* __restrict__ coors, unsigned short* __restrict__ grid) {
    int n = blockIdx.x * 256 + threadIdx.x;
    if (n >= NVOX) return;
    int b = coors[4*n+0], z = coors[4*n+1], y = coors[4*n+2], x = coors[4*n+3];
    grid[((b*PD + z+1)*PH + y+1)*PW + x+1] = (unsigned short)(n + 1);
}

// ---- subm conv 1: 128 -> 16, ReLU. block = 16 voxels x 16 d; nbr in-block ----
__global__ void k_subm1(const float* __restrict__ feat, const float* __restrict__ W1,
                        const int* __restrict__ coors, const unsigned short* __restrict__ grid,
                        float* __restrict__ x1) {
    __shared__ int s_base[16];
    __shared__ int s_cnt[16];
    __shared__ int s_list[16][27];
    int base = blockIdx.x * 16;            // NVOX % 16 == 0
    int t = threadIdx.x;
    if (t < 16) {
        int n = base + t;
        int b = coors[4*n+0], z = coors[4*n+1], y = coors[4*n+2], x = coors[4*n+3];
        s_base[t] = ((b*PD + z)*PH + y)*PW + x;   // tap k adds dz*PH*PW+dy*PW+dx
        s_cnt[t] = 0;
    }
    __syncthreads();
    for (int i = t; i < 16*27; i += 256) {
        int v = i / 27, k = i % 27;
        int dz = k / 9, dy = (k / 3) % 3, dx = k % 3;
        int id = (int)grid[s_base[v] + dz*(PH*PW) + dy*PW + dx] - 1;
        if (id >= 0) {
            int pos = atomicAdd(&s_cnt[v], 1);
            s_list[v][pos] = (k << 16) | id;
        }
    }
    __syncthreads();
    int v = t >> 4, d = t & 15;
    int cnt = s_cnt[v];
    float acc = 0.f;
    for (int tap = 0; tap < cnt; ++tap) {
        int pk = s_list[v][tap];
        int k = pk >> 16, idx = pk & 0xFFFF;
        const float4* f4 = (const float4*)(feat + (size_t)idx * C1);
        const float* w = W1 + k * (C1*16) + d;
        #pragma unroll 8
        for (int c4 = 0; c4 < 32; ++c4) {
            float4 f = f4[c4];
            acc += f.x * w[(c4*4+0)*16];
            acc += f.y * w[(c4*4+1)*16];
            acc += f.z * w[(c4*4+2)*16];
            acc += f.w * w[(c4*4+3)*16];
        }
    }
    x1[(base + v)*16 + d] = fmaxf(acc, 0.f);
}

// ---- subm conv 2: 16 -> 16, ReLU. same structure ----
__global__ void k_subm2(const float* __restrict__ x1, const float* __restrict__ W2,
                        const int* __restrict__ coors, const unsigned short* __restrict__ grid,
                        float* __restrict__ x2) {
    __shared__ int s_base[16];
    __shared__ int s_cnt[16];
    __shared__ int s_list[16][27];
    int base = blockIdx.x * 16;
    int t = threadIdx.x;
    if (t < 16) {
        int n = base + t;
        int b = coors[4*n+0], z = coors[4*n+1], y = coors[4*n+2], x = coors[4*n+3];
        s_base[t] = ((b*PD + z)*PH + y)*PW + x;
        s_cnt[t] = 0;
    }
    __syncthreads();
    for (int i = t; i < 16*27; i += 256) {
        int v = i / 27, k = i % 27;
        int dz = k / 9, dy = (k / 3) % 3, dx = k % 3;
        int id = (int)grid[s_base[v] + dz*(PH*PW) + dy*PW + dx] - 1;
        if (id >= 0) {
            int pos = atomicAdd(&s_cnt[v], 1);
            s_list[v][pos] = (k << 16) | id;
        }
    }
    __syncthreads();
    int v = t >> 4, d = t & 15;
    int cnt = s_cnt[v];
    float acc = 0.f;
    for (int tap = 0; tap < cnt; ++tap) {
        int pk = s_list[v][tap];
        int k = pk >> 16, idx = pk & 0xFFFF;
        const float4* xr = (const float4*)(x1 + (size_t)idx * 16);
        float4 a0 = xr[0], a1 = xr[1], a2 = xr[2], a3 = xr[3];
        const float* w = W2 + k * 256 + d;
        acc += a0.x*w[0*16]  + a0.y*w[1*16]  + a0.z*w[2*16]  + a0.w*w[3*16]
             + a1.x*w[4*16]  + a1.y*w[5*16]  + a1.z*w[6*16]  + a1.w*w[7*16]
             + a2.x*w[8*16]  + a2.y*w[9*16]  + a2.z*w[10*16] + a2.w*w[11*16]
             + a3.x*w[12*16] + a3.y*w[13*16] + a3.z*w[14*16] + a3.w*w[15*16];
    }
    x2[(base + v)*16 + d] = fmaxf(acc, 0.f);
}

// ---- stride-2 conv 16 -> 32 as scatter: block = 8 voxels x 32 channels ----
__global__ void k_scatter(const float* __restrict__ x2, const float* __restrict__ W3,
                          const int* __restrict__ coors, float* __restrict__ out) {
    int v = threadIdx.x >> 5, d = threadIdx.x & 31;
    int n = blockIdx.x * 8 + v;
    if (n >= NVOX) return;
    int b  = coors[4*n+0];
    int zp = coors[4*n+1] + 1, yp = coors[4*n+2] + 1, xp = coors[4*n+3] + 1;
    int dz[2], pz[2], dy[2], py[2], dx[2], px[2];
    int nz = axis_taps(zp, DO_, dz, pz);
    int ny = axis_taps(yp, HO_, dy, py);
    int nx = axis_taps(xp, WO_, dx, px);
    const float4* xr = (const float4*)(x2 + (size_t)n * 16);
    float r[16];
    *(float4*)(r + 0)  = xr[0];
    *(float4*)(r + 4)  = xr[1];
    *(float4*)(r + 8)  = xr[2];
    *(float4*)(r + 12) = xr[3];
    int bofs = b * OPP;
    for (int iz = 0; iz < nz; ++iz)
        for (int iy = 0; iy < ny; ++iy)
            for (int ix = 0; ix < nx; ++ix) {
                int k = dz[iz]*9 + dy[iy]*3 + dx[ix];
                int p = bofs + (pz[iz]*HO_ + py[iy])*WO_ + px[ix];
                const float* w = W3 + k*512 + d;   // coalesced 128B across d
                float acc = 0.f;
                #pragma unroll
                for (int c = 0; c < 16; ++c) acc += r[c] * w[c * 32];
                atomicAdd(out + (size_t)p * 32 + d, acc);
            }
}

// ---- idempotent ReLU over touched positions ----
__global__ void k_relu(const int* __restrict__ coors, float* __restrict__ out) {
    int v = threadIdx.x >> 5, d = threadIdx.x & 31;
    int n = blockIdx.x * 8 + v;
    if (n >= NVOX) return;
    int b  = coors[4*n+0];
    int zp = coors[4*n+1] + 1, yp = coors[4*n+2] + 1, xp = coors[4*n+3] + 1;
    int dz[2], pz[2], dy[2], py[2], dx[2], px[2];
    int nz = axis_taps(zp, DO_, dz, pz);
    int ny = axis_taps(yp, HO_, dy, py);
    int nx = axis_taps(xp, WO_, dx, px);
    int bofs = b * OPP;
    for (int iz = 0; iz < nz; ++iz)
        for (int iy = 0; iy < ny; ++iy)
            for (int ix = 0; ix < nx; ++ix) {
                int p = bofs + (pz[iz]*HO_ + py[iy])*WO_ + px[ix];
                size_t o = (size_t)p * 32 + d;
                out[o] = fmaxf(out[o], 0.f);
            }
}

extern "C" void kernel_launch(void* const* d_in, const int* in_sizes, int n_in,
                              void* d_out, int out_size, void* d_ws, size_t ws_size,
                              hipStream_t stream) {
    const float* feat  = (const float*)d_in[0];  // f32 (N,128)
    const int*   coors = (const int*)d_in[1];    // int32 (N,4)
    const float* W1    = (const float*)d_in[2];  // f32 (27,128,16)
    const float* W2    = (const float*)d_in[3];  // f32 (27,16,16)
    const float* W3    = (const float*)d_in[4];  // f32 (27,16,32)
    float* out = (float*)d_out;                  // f32 (2,21,200,176,32)

    char* ws = (char*)d_ws;
    size_t off = 0;
    unsigned short* grid = (unsigned short*)(ws + off);
    off += (((size_t)GRID_CELLS*2) + 255) & ~(size_t)255;
    float* x1 = (float*)(ws + off); off += (((size_t)NVOX*16*4) + 255) & ~(size_t)255;
    float* x2 = (float*)(ws + off);

    // runtime fill path measured at 6.6 TB/s (poison fills) - use it, never
    // hand-rolled zero kernels (measured 2-3 TB/s in R5/R7).
    hipMemsetAsync(grid, 0x00, (size_t)GRID_CELLS * 2, stream);
    hipMemsetAsync(out,  0x00, (size_t)out_size * sizeof(float), stream);
    k_build <<<(NVOX + 255) / 256, 256, 0, stream>>>(coors, grid);
    k_subm1 <<<NVOX / 16, 256, 0, stream>>>(feat, W1, coors, grid, x1);
    k_subm2 <<<NVOX / 16, 256, 0, stream>>>(x1, W2, coors, grid, x2);
    k_scatter<<<NVOX / 8, 256, 0, stream>>>(x2, W3, coors, out);
    k_relu  <<<NVOX / 8, 256, 0, stream>>>(coors, out);
}